// Round 7
// baseline (254.456 us; speedup 1.0000x reference)
//
#include <hip/hip_runtime.h>

#define B_    8
#define C_    1024
#define HID   64
#define N_    2048
#define RTOT  192

typedef __attribute__((ext_vector_type(8))) short   bf16x8;
typedef __attribute__((ext_vector_type(8))) unsigned short ush8;
typedef __attribute__((ext_vector_type(4))) unsigned short ush4;
typedef __attribute__((ext_vector_type(4))) float   f32x4;

// ---- workspace byte offsets ----
#define WSB_WBF   ((size_t)0)          // [192][1024]     bf16
#define WSB_TPG   ((size_t)393216)     // [B][192][2048]  bf16
#define WSB_THT   ((size_t)6684672)    // [B][2048][64]   bf16
#define WSB_M     ((size_t)8781824)    // [B][64][64]     f32
#define WSB_G     ((size_t)8912896)    // [B][64][64]     f32
#define WSB_S     ((size_t)9043968)    // [B][64]         f32 (contiguous after G)
#define WSB_WMBF  ((size_t)9046016)    // [B][1024][64]   bf16
#define WSB_SC    ((size_t)10094592)   // [1024] f32
#define WSB_SH    ((size_t)10098688)   // [1024] f32
#define WSB_XT    ((size_t)10102784)   // [B][2048][1024] bf16 (32 MB)

static __device__ __forceinline__ unsigned short f2bf(float f) {
    union { float f; unsigned u; } v; v.f = f;
    unsigned r = v.u + 0x7fffu + ((v.u >> 16) & 1u);
    return (unsigned short)(r >> 16);
}
static __device__ __forceinline__ float bf2f(unsigned short h) {
    union { unsigned u; float f; } v; v.u = ((unsigned)h) << 16;
    return v.f;
}

// async global->LDS DMA, 16B per lane. LDS dest must be linear in lane order.
static __device__ __forceinline__ void gload16(const unsigned short* g, unsigned short* l) {
    __builtin_amdgcn_global_load_lds(
        (const __attribute__((address_space(1))) unsigned int*)g,
        (__attribute__((address_space(3))) unsigned int*)l, 16, 0, 0);
}

// K0 (fused): z<8 -> x-transpose slice for batch z; z==8 -> weight cvt.
// Merging independent prologue work removes one kernel boundary.
__global__ __launch_bounds__(256) void prep(
    const float* __restrict__ x, unsigned short* __restrict__ xT,
    const float* __restrict__ tw, const float* __restrict__ pw,
    const float* __restrict__ gw, unsigned short* __restrict__ wbf)
{
    const int t = threadIdx.x;
    if (blockIdx.z == 8) {
        // ---- wcvt: 196608 elems over 512 blocks x 256 thr x 2 reps ----
        const int bid = blockIdx.y * 32 + blockIdx.x;     // 0..511
#pragma unroll
        for (int rep = 0; rep < 2; rep++) {
            int idx = bid * 512 + rep * 256 + t;
            if (idx < RTOT * 1024) {
                int r = idx >> 10, k = idx & 1023;
                float v = (r < 64) ? tw[(size_t)r * 1024 + k]
                        : (r < 128) ? pw[(size_t)(r - 64) * 1024 + k]
                                    : gw[(size_t)(r - 128) * 1024 + k];
                wbf[idx] = f2bf(v);
            }
        }
        return;
    }
    // ---- xpose: x [B][C][N] f32 -> xT [B][N][C] bf16, 64x64 LDS tile ----
    const int n0 = blockIdx.x * 64, c0 = blockIdx.y * 64, b = blockIdx.z;
    __shared__ unsigned short tile[64][66];

    const float* xb = x + ((size_t)b * C_ + c0) * N_ + n0;
#pragma unroll
    for (int p = 0; p < 2; p++) {
        const int m  = t & 15;            // n-quad: n_local = 4m..4m+3
        const int cp = (t >> 4) + 16 * p; // c-pair index 0..31
        const int cl = 2 * cp;
        f32x4 v0 = *(const f32x4*)(xb + (size_t)cl * N_ + m * 4);
        f32x4 v1 = *(const f32x4*)(xb + (size_t)(cl + 1) * N_ + m * 4);
#pragma unroll
        for (int r2 = 0; r2 < 4; r2++) {
            unsigned val = (unsigned)f2bf(v0[r2]) | ((unsigned)f2bf(v1[r2]) << 16);
            *(unsigned*)&tile[m * 4 + r2][cl] = val;
        }
    }
    __syncthreads();
    unsigned short* ob = xT + ((size_t)b * N_ + n0) * C_ + c0;
#pragma unroll
    for (int r = 0; r < 2; r++) {
        const int nl   = (t >> 3) + 32 * r;
        const int c8   = (t & 7) * 8;
        uint4 u;
        u.x = *(unsigned*)&tile[nl][c8];
        u.y = *(unsigned*)&tile[nl][c8 + 2];
        u.z = *(unsigned*)&tile[nl][c8 + 4];
        u.w = *(unsigned*)&tile[nl][c8 + 6];
        *(uint4*)(ob + (size_t)nl * C_ + c8) = u;
    }
}

// K1: projection GEMM, T3 2-phase pipeline with global_load_lds staging.
// Block = 64n x 96r, BK=64, 4 waves: wave (wn,wc) owns 32n x 48r. Double-
// buffered LDS; stage(s+1) before compute(s); one vmcnt(0)+barrier per step.
// XOR swizzle (slot ^= row&7): linear LDS dest + inverse-swizzled global
// source + swizzled ds_read.
__global__ __launch_bounds__(256, 4) void proj_mfma(
    const unsigned short* __restrict__ xT, const unsigned short* __restrict__ wbf,
    const float* __restrict__ tb, const float* __restrict__ pb,
    const float* __restrict__ gb, unsigned short* __restrict__ tpgbf,
    unsigned short* __restrict__ thT)
{
    const int b = blockIdx.z, rh = blockIdx.y, n0 = blockIdx.x * 64;
    const int t = threadIdx.x, w = t >> 6, L = t & 63;
    const int wn = w & 1, wc = w >> 1;
    const int lr = L & 15, q = L >> 4;

    __shared__ unsigned short Abuf[2][64][64];   // 16 KB
    __shared__ unsigned short Bbuf[2][96][64];   // 24 KB

    f32x4 acc[2][3] = {};

    auto stage = [&](int cb, int k0) {
#pragma unroll
        for (int i = 0; i < 2; i++) {            // A: 8 KB = 2 chunks
            int o = (i * 256 + t) * 16;
            int row = o >> 7, slot = (o >> 4) & 7, ss = slot ^ (row & 7);
            gload16(xT + ((size_t)b * N_ + n0 + row) * C_ + k0 + ss * 8,
                    &Abuf[cb][0][0] + o / 2);
        }
#pragma unroll
        for (int i = 0; i < 3; i++) {            // B: 12 KB = 3 chunks
            int o = (i * 256 + t) * 16;
            int row = o >> 7, slot = (o >> 4) & 7, ss = slot ^ (row & 7);
            gload16(wbf + ((size_t)(96 * rh + row)) * 1024 + k0 + ss * 8,
                    &Bbuf[cb][0][0] + o / 2);
        }
    };

    int cur = 0;
    stage(0, 0);
    asm volatile("s_waitcnt vmcnt(0)" ::: "memory");
    __syncthreads();

    const int swz = lr & 7;
    for (int s = 0; s < 16; s++) {
        if (s < 15) stage(cur ^ 1, (s + 1) * 64);   // prefetch next tile
#pragma unroll
        for (int ksub = 0; ksub < 2; ksub++) {
            bf16x8 Af[2], Bf[3];
#pragma unroll
            for (int fa = 0; fa < 2; fa++)
                Af[fa] = *(const bf16x8*)&Abuf[cur][wn * 32 + fa * 16 + lr]
                                               [((ksub * 4 + q) ^ swz) * 8];
#pragma unroll
            for (int j = 0; j < 3; j++)
                Bf[j] = *(const bf16x8*)&Bbuf[cur][wc * 48 + j * 16 + lr]
                                              [((ksub * 4 + q) ^ swz) * 8];
#pragma unroll
            for (int fa = 0; fa < 2; fa++)
#pragma unroll
                for (int j = 0; j < 3; j++)
                    acc[fa][j] = __builtin_amdgcn_mfma_f32_16x16x32_bf16(
                        Af[fa], Bf[j], acc[fa][j], 0, 0, 0);
        }
        asm volatile("s_waitcnt vmcnt(0)" ::: "memory");
        __syncthreads();
        cur ^= 1;
    }

#pragma unroll
    for (int fa = 0; fa < 2; fa++)
#pragma unroll
        for (int j = 0; j < 3; j++) {
            int rcol = 96 * rh + 48 * wc + 16 * j + lr;
            float bias = (rcol < 64) ? tb[rcol]
                       : (rcol < 128) ? pb[rcol - 64] : gb[rcol - 128];
            ush4 o;
#pragma unroll
            for (int rr = 0; rr < 4; rr++) o[rr] = f2bf(acc[fa][j][rr] + bias);
            int nglob = n0 + wn * 32 + fa * 16 + q * 4;
            *(ush4*)(tpgbf + ((size_t)b * RTOT + rcol) * N_ + nglob) = o;
            if (rcol < HID) {   // theta rows: transposed copy for finalk
#pragma unroll
                for (int rr = 0; rr < 4; rr++)
                    thT[((size_t)b * N_ + nglob + rr) * HID + rcol] = o[rr];
            }
        }
}

// K2: gram products via MFMA, FULL K per block (grid 2 x 8), direct stores.
// p==0: M = phi·g^T ; p==1: G = theta·theta^T plus S = theta·1.
// Each block exclusively owns its (p,b) output -> no atomics, no reduce pass.
__global__ __launch_bounds__(256) void gram_mfma(
    const unsigned short* __restrict__ tpgbf, float* __restrict__ Mm,
    float* __restrict__ Gg, float* __restrict__ S)
{
    const int p = blockIdx.x, b = blockIdx.y;
    const int t = threadIdx.x, w = t >> 6, L = t & 63;
    const int lr = L & 15, q = L >> 4;
    const unsigned short* base = tpgbf + (size_t)b * RTOT * N_;
    const unsigned short* Arow = base + (p ? 0 : (size_t)64 * N_);
    const unsigned short* Brow = base + (p ? 0 : (size_t)128 * N_);
    const unsigned short* ap = Arow + ((size_t)(16 * w + lr)) * N_ + q * 8;
    const unsigned short* bp = Brow + ((size_t)lr) * N_ + q * 8;

    bf16x8 ones;
#pragma unroll
    for (int j = 0; j < 8; j++) ones[j] = (short)0x3F80;

    f32x4 acc[4] = {};
    f32x4 accs = {};
#pragma unroll 4
    for (int it = 0; it < 64; ++it) {
        const int kn = it * 32;
        bf16x8 a = *(const bf16x8*)(ap + kn);
#pragma unroll
        for (int g = 0; g < 4; g++) {
            bf16x8 bb = *(const bf16x8*)(bp + (size_t)g * 16 * N_ + kn);
            acc[g] = __builtin_amdgcn_mfma_f32_16x16x32_bf16(a, bb, acc[g], 0, 0, 0);
        }
        if (p) accs = __builtin_amdgcn_mfma_f32_16x16x32_bf16(a, ones, accs, 0, 0, 0);
    }
    float* outp = (p ? Gg : Mm) + (size_t)b * HID * HID;
#pragma unroll
    for (int g = 0; g < 4; g++)
#pragma unroll
        for (int r = 0; r < 4; r++) {
            int row = 16 * w + q * 4 + r, col = 16 * g + lr;
            outp[row * HID + col] = acc[g][r];
        }
    if (p && lr == 0) {
#pragma unroll
        for (int r = 0; r < 4; r++)
            S[b * HID + 16 * w + q * 4 + r] = accs[r];
    }
}

// K3: fused wmk + statsk. One block per channel c; 8 waves = 8 batches in
// parallel; G-row loads vectorized f32x4.
__global__ __launch_bounds__(512) void wmstat(
    const float* __restrict__ ww, const float* __restrict__ Mm,
    const float* __restrict__ S, const float* __restrict__ G,
    const float* __restrict__ wb, const float* __restrict__ gamma,
    const float* __restrict__ beta, unsigned short* __restrict__ wmbf,
    float* __restrict__ scale, float* __restrict__ shift2)
{
    const int c = blockIdx.x;
    const int t = threadIdx.x;
    const int b = t >> 6, lane = t & 63;
    const float wbc = wb[c];
    const float* wr = ww + (size_t)c * HID;

    const float* mr = Mm + ((size_t)b * HID + lane) * HID;
    float acc = 0.f;
#pragma unroll
    for (int d = 0; d < HID; d += 4) {
        float4 m4 = *(const float4*)(mr + d);
        acc += wr[d] * m4.x + wr[d + 1] * m4.y + wr[d + 2] * m4.z + wr[d + 3] * m4.w;
    }
    unsigned short us = f2bf(acc * (1.0f / N_));
    wmbf[((size_t)b * C_ + c) * HID + lane] = us;
    float v = bf2f(us);
    float sv = S[b * HID + lane];
    float t1 = v * sv;
    for (int off = 32; off; off >>= 1) t1 += __shfl_down(t1, off);
    t1 = __shfl(t1, 0);

    const f32x4* Gb4 = (const f32x4*)(G + (size_t)b * HID * HID + (size_t)lane * HID);
    float inner = 0.f;
#pragma unroll
    for (int fo = 0; fo < 16; fo++) {
        f32x4 g4 = Gb4[fo];
        inner = fmaf(g4[0], __shfl(v, 4 * fo + 0), inner);
        inner = fmaf(g4[1], __shfl(v, 4 * fo + 1), inner);
        inner = fmaf(g4[2], __shfl(v, 4 * fo + 2), inner);
        inner = fmaf(g4[3], __shfl(v, 4 * fo + 3), inner);
    }
    float qq = v * inner;
    for (int off = 32; off; off >>= 1) qq += __shfl_down(qq, off);
    qq = __shfl(qq, 0);

    __shared__ float red[16];
    if (lane == 0) {
        red[b] = t1;
        red[8 + b] = qq + 2.f * wbc * t1;
    }
    __syncthreads();
    if (t == 0) {
        float asum = 0.f, asq = 0.f;
#pragma unroll
        for (int i = 0; i < 8; i++) { asum += red[i]; asq += red[8 + i]; }
        const float cnt = (float)B_ * (float)N_;
        const float inv = 1.0f / cnt;
        float mean = (asum + cnt * wbc) * inv;
        float e2   = (asq + cnt * wbc * wbc) * inv;
        float var  = e2 - mean * mean;
        float sc   = gamma[c] * rsqrtf(var + 1e-5f);
        scale[c]  = sc;
        shift2[c] = beta[c] - mean * sc + sc * wbc;
    }
}

// K4: out = sc[c]*(Wm[b][c][:]·theta[:,n]) + sh[c] + x  (float4 stores along n)
__global__ __launch_bounds__(256) void finalk_mfma(
    const unsigned short* __restrict__ wmbf, const unsigned short* __restrict__ thT,
    const float* __restrict__ x, const float* __restrict__ scale,
    const float* __restrict__ shift2, float* __restrict__ out)
{
    const int b = blockIdx.z, c0 = blockIdx.y * 64, n0 = blockIdx.x * 64;
    const int t = threadIdx.x, w = t >> 6, L = t & 63;
    const int lr = L & 15, q = L >> 4;

    const unsigned short* ap = thT + ((size_t)b * N_ + n0 + 16 * w + lr) * HID + q * 8;
    const unsigned short* bp = wmbf + ((size_t)b * C_ + c0 + lr) * HID + q * 8;

    float4 xv[4];
    size_t xoff[4];
#pragma unroll
    for (int g = 0; g < 4; g++) {
        xoff[g] = ((size_t)b * C_ + c0 + 16 * g + lr) * N_ + n0 + 16 * w + q * 4;
        xv[g] = *(const float4*)(x + xoff[g]);
    }

    bf16x8 A0 = *(const bf16x8*)(ap);
    bf16x8 A1 = *(const bf16x8*)(ap + 32);
    f32x4 acc[4] = {};
#pragma unroll
    for (int g = 0; g < 4; g++) {
        bf16x8 Bg0 = *(const bf16x8*)(bp + (size_t)g * 16 * HID);
        bf16x8 Bg1 = *(const bf16x8*)(bp + (size_t)g * 16 * HID + 32);
        acc[g] = __builtin_amdgcn_mfma_f32_16x16x32_bf16(A0, Bg0, acc[g], 0, 0, 0);
        acc[g] = __builtin_amdgcn_mfma_f32_16x16x32_bf16(A1, Bg1, acc[g], 0, 0, 0);
    }
#pragma unroll
    for (int g = 0; g < 4; g++) {
        int c = c0 + 16 * g + lr;
        float sc = scale[c], sh = shift2[c];
        float4 o;
        o.x = fmaf(sc, acc[g][0], sh) + xv[g].x;
        o.y = fmaf(sc, acc[g][1], sh) + xv[g].y;
        o.z = fmaf(sc, acc[g][2], sh) + xv[g].z;
        o.w = fmaf(sc, acc[g][3], sh) + xv[g].w;
        *(float4*)(out + xoff[g]) = o;
    }
}

extern "C" void kernel_launch(void* const* d_in, const int* in_sizes, int n_in,
                              void* d_out, int out_size, void* d_ws, size_t ws_size,
                              hipStream_t stream)
{
    const float* x  = (const float*)d_in[0];
    const float* tw = (const float*)d_in[1];
    const float* tb = (const float*)d_in[2];
    const float* pw = (const float*)d_in[3];
    const float* pb = (const float*)d_in[4];
    const float* gw = (const float*)d_in[5];
    const float* gb = (const float*)d_in[6];
    const float* ww = (const float*)d_in[7];
    const float* wb = (const float*)d_in[8];
    const float* gamma = (const float*)d_in[9];
    const float* beta  = (const float*)d_in[10];
    float* out = (float*)d_out;

    char* ws = (char*)d_ws;
    unsigned short* wbf   = (unsigned short*)(ws + WSB_WBF);
    unsigned short* tpgbf = (unsigned short*)(ws + WSB_TPG);
    unsigned short* thT   = (unsigned short*)(ws + WSB_THT);
    float* Mm   = (float*)(ws + WSB_M);
    float* Gg   = (float*)(ws + WSB_G);
    float* S    = (float*)(ws + WSB_S);
    unsigned short* wmbf = (unsigned short*)(ws + WSB_WMBF);
    float* scl  = (float*)(ws + WSB_SC);
    float* shf  = (float*)(ws + WSB_SH);
    unsigned short* xT = (unsigned short*)(ws + WSB_XT);

    prep<<<dim3(32, 16, 9), 256, 0, stream>>>(x, xT, tw, pw, gw, wbf);
    proj_mfma<<<dim3(32, 2, B_), 256, 0, stream>>>(xT, wbf, tb, pb, gb, tpgbf, thT);
    gram_mfma<<<dim3(2, B_), 256, 0, stream>>>(tpgbf, Mm, Gg, S);
    wmstat<<<C_, 512, 0, stream>>>(ww, Mm, S, Gg, wb, gamma, beta, wmbf, scl, shf);
    finalk_mfma<<<dim3(32, 16, B_), 256, 0, stream>>>(wmbf, thT, x, scl, shf, out);
}

// Round 8
// 215.493 us; speedup vs baseline: 1.1808x; 1.1808x over previous
//
#include <hip/hip_runtime.h>

#define B_    8
#define C_    1024
#define HID   64
#define N_    2048
#define RTOT  192

typedef __attribute__((ext_vector_type(8))) short   bf16x8;
typedef __attribute__((ext_vector_type(8))) unsigned short ush8;
typedef __attribute__((ext_vector_type(4))) unsigned short ush4;
typedef __attribute__((ext_vector_type(4))) float   f32x4;

// ---- workspace byte offsets ----
#define WSB_WBF   ((size_t)0)          // [192][1024]     bf16
#define WSB_TPG   ((size_t)393216)     // [B][192][2048]  bf16
#define WSB_THT   ((size_t)6684672)    // [B][2048][64]   bf16
#define WSB_M     ((size_t)8781824)    // [B][64][64]     f32
#define WSB_G     ((size_t)8912896)    // [B][64][64]     f32
#define WSB_S     ((size_t)9043968)    // [B][64]         f32 (contiguous after G)
#define WSB_WMBF  ((size_t)9046016)    // [B][1024][64]   bf16
#define WSB_SC    ((size_t)10094592)   // [1024] f32
#define WSB_SH    ((size_t)10098688)   // [1024] f32
#define WSB_XT    ((size_t)10102784)   // [B][2048][1024] bf16 (32 MB)
// gram partials ALIAS the xT region (xT dead after proj; stream-ordered):
#define WSB_P     WSB_XT               // [16 kc][66048] f32 (M 32768 | G 32768 | S 512)
#define PSTRIDE   66048
#define POFF_G    32768
#define POFF_S    65536
#define NKC       16

static __device__ __forceinline__ unsigned short f2bf(float f) {
    union { float f; unsigned u; } v; v.f = f;
    unsigned r = v.u + 0x7fffu + ((v.u >> 16) & 1u);
    return (unsigned short)(r >> 16);
}
static __device__ __forceinline__ float bf2f(unsigned short h) {
    union { unsigned u; float f; } v; v.u = ((unsigned)h) << 16;
    return v.f;
}

// async global->LDS DMA, 16B per lane. LDS dest must be linear in lane order.
static __device__ __forceinline__ void gload16(const unsigned short* g, unsigned short* l) {
    __builtin_amdgcn_global_load_lds(
        (const __attribute__((address_space(1))) unsigned int*)g,
        (__attribute__((address_space(3))) unsigned int*)l, 16, 0, 0);
}

// K0 (fused): z<8 -> x-transpose slice for batch z; z==8 -> weight cvt.
__global__ __launch_bounds__(256) void prep(
    const float* __restrict__ x, unsigned short* __restrict__ xT,
    const float* __restrict__ tw, const float* __restrict__ pw,
    const float* __restrict__ gw, unsigned short* __restrict__ wbf)
{
    const int t = threadIdx.x;
    if (blockIdx.z == 8) {
        const int bid = blockIdx.y * 32 + blockIdx.x;     // 0..511
#pragma unroll
        for (int rep = 0; rep < 2; rep++) {
            int idx = bid * 512 + rep * 256 + t;
            if (idx < RTOT * 1024) {
                int r = idx >> 10, k = idx & 1023;
                float v = (r < 64) ? tw[(size_t)r * 1024 + k]
                        : (r < 128) ? pw[(size_t)(r - 64) * 1024 + k]
                                    : gw[(size_t)(r - 128) * 1024 + k];
                wbf[idx] = f2bf(v);
            }
        }
        return;
    }
    // ---- xpose: x [B][C][N] f32 -> xT [B][N][C] bf16, 64x64 LDS tile ----
    const int n0 = blockIdx.x * 64, c0 = blockIdx.y * 64, b = blockIdx.z;
    __shared__ unsigned short tile[64][66];

    const float* xb = x + ((size_t)b * C_ + c0) * N_ + n0;
#pragma unroll
    for (int p = 0; p < 2; p++) {
        const int m  = t & 15;            // n-quad: n_local = 4m..4m+3
        const int cp = (t >> 4) + 16 * p; // c-pair index 0..31
        const int cl = 2 * cp;
        f32x4 v0 = *(const f32x4*)(xb + (size_t)cl * N_ + m * 4);
        f32x4 v1 = *(const f32x4*)(xb + (size_t)(cl + 1) * N_ + m * 4);
#pragma unroll
        for (int r2 = 0; r2 < 4; r2++) {
            unsigned val = (unsigned)f2bf(v0[r2]) | ((unsigned)f2bf(v1[r2]) << 16);
            *(unsigned*)&tile[m * 4 + r2][cl] = val;
        }
    }
    __syncthreads();
    unsigned short* ob = xT + ((size_t)b * N_ + n0) * C_ + c0;
#pragma unroll
    for (int r = 0; r < 2; r++) {
        const int nl   = (t >> 3) + 32 * r;
        const int c8   = (t & 7) * 8;
        uint4 u;
        u.x = *(unsigned*)&tile[nl][c8];
        u.y = *(unsigned*)&tile[nl][c8 + 2];
        u.z = *(unsigned*)&tile[nl][c8 + 4];
        u.w = *(unsigned*)&tile[nl][c8 + 6];
        *(uint4*)(ob + (size_t)nl * C_ + c8) = u;
    }
}

// K1: projection GEMM, T3 2-phase pipeline with global_load_lds staging.
// Block = 64n x 96r, BK=64, 4 waves: wave (wn,wc) owns 32n x 48r. Double-
// buffered LDS; stage(s+1) before compute(s); one vmcnt(0)+barrier per step.
// XOR swizzle (slot ^= row&7): linear LDS dest + inverse-swizzled global
// source + swizzled ds_read.
__global__ __launch_bounds__(256, 4) void proj_mfma(
    const unsigned short* __restrict__ xT, const unsigned short* __restrict__ wbf,
    const float* __restrict__ tb, const float* __restrict__ pb,
    const float* __restrict__ gb, unsigned short* __restrict__ tpgbf,
    unsigned short* __restrict__ thT)
{
    const int b = blockIdx.z, rh = blockIdx.y, n0 = blockIdx.x * 64;
    const int t = threadIdx.x, w = t >> 6, L = t & 63;
    const int wn = w & 1, wc = w >> 1;
    const int lr = L & 15, q = L >> 4;

    __shared__ unsigned short Abuf[2][64][64];   // 16 KB
    __shared__ unsigned short Bbuf[2][96][64];   // 24 KB

    f32x4 acc[2][3] = {};

    auto stage = [&](int cb, int k0) {
#pragma unroll
        for (int i = 0; i < 2; i++) {            // A: 8 KB = 2 chunks
            int o = (i * 256 + t) * 16;
            int row = o >> 7, slot = (o >> 4) & 7, ss = slot ^ (row & 7);
            gload16(xT + ((size_t)b * N_ + n0 + row) * C_ + k0 + ss * 8,
                    &Abuf[cb][0][0] + o / 2);
        }
#pragma unroll
        for (int i = 0; i < 3; i++) {            // B: 12 KB = 3 chunks
            int o = (i * 256 + t) * 16;
            int row = o >> 7, slot = (o >> 4) & 7, ss = slot ^ (row & 7);
            gload16(wbf + ((size_t)(96 * rh + row)) * 1024 + k0 + ss * 8,
                    &Bbuf[cb][0][0] + o / 2);
        }
    };

    int cur = 0;
    stage(0, 0);
    asm volatile("s_waitcnt vmcnt(0)" ::: "memory");
    __syncthreads();

    const int swz = lr & 7;
    for (int s = 0; s < 16; s++) {
        if (s < 15) stage(cur ^ 1, (s + 1) * 64);   // prefetch next tile
#pragma unroll
        for (int ksub = 0; ksub < 2; ksub++) {
            bf16x8 Af[2], Bf[3];
#pragma unroll
            for (int fa = 0; fa < 2; fa++)
                Af[fa] = *(const bf16x8*)&Abuf[cur][wn * 32 + fa * 16 + lr]
                                               [((ksub * 4 + q) ^ swz) * 8];
#pragma unroll
            for (int j = 0; j < 3; j++)
                Bf[j] = *(const bf16x8*)&Bbuf[cur][wc * 48 + j * 16 + lr]
                                              [((ksub * 4 + q) ^ swz) * 8];
#pragma unroll
            for (int fa = 0; fa < 2; fa++)
#pragma unroll
                for (int j = 0; j < 3; j++)
                    acc[fa][j] = __builtin_amdgcn_mfma_f32_16x16x32_bf16(
                        Af[fa], Bf[j], acc[fa][j], 0, 0, 0);
        }
        asm volatile("s_waitcnt vmcnt(0)" ::: "memory");
        __syncthreads();
        cur ^= 1;
    }

#pragma unroll
    for (int fa = 0; fa < 2; fa++)
#pragma unroll
        for (int j = 0; j < 3; j++) {
            int rcol = 96 * rh + 48 * wc + 16 * j + lr;
            float bias = (rcol < 64) ? tb[rcol]
                       : (rcol < 128) ? pb[rcol - 64] : gb[rcol - 128];
            ush4 o;
#pragma unroll
            for (int rr = 0; rr < 4; rr++) o[rr] = f2bf(acc[fa][j][rr] + bias);
            int nglob = n0 + wn * 32 + fa * 16 + q * 4;
            *(ush4*)(tpgbf + ((size_t)b * RTOT + rcol) * N_ + nglob) = o;
            if (rcol < HID) {   // theta rows: transposed copy for finalk
#pragma unroll
                for (int rr = 0; rr < 4; rr++)
                    thT[((size_t)b * N_ + nglob + rr) * HID + rcol] = o[rr];
            }
        }
}

// K2: gram products via MFMA, k-split (16 chunks -> 256 blocks = 1/CU),
// PLAIN STORES into per-kc partial buffers. p==0: M = phi·g^T ;
// p==1: G = theta·theta^T plus S = theta·1.
__global__ __launch_bounds__(256) void gram_mfma(
    const unsigned short* __restrict__ tpgbf, float* __restrict__ P)
{
    const int kc = blockIdx.x, p = blockIdx.y, b = blockIdx.z;
    const int t = threadIdx.x, w = t >> 6, L = t & 63;
    const int lr = L & 15, q = L >> 4;
    const unsigned short* base = tpgbf + (size_t)b * RTOT * N_;
    const unsigned short* Arow = base + (p ? 0 : (size_t)64 * N_);
    const unsigned short* Brow = base + (p ? 0 : (size_t)128 * N_);
    const unsigned short* ap = Arow + ((size_t)(16 * w + lr)) * N_ + kc * 128 + q * 8;
    const unsigned short* bp = Brow + ((size_t)lr) * N_ + kc * 128 + q * 8;

    bf16x8 ones;
#pragma unroll
    for (int j = 0; j < 8; j++) ones[j] = (short)0x3F80;

    f32x4 acc[4] = {};
    f32x4 accs = {};
#pragma unroll
    for (int it = 0; it < 4; ++it) {
        const int kn = it * 32;
        bf16x8 a = *(const bf16x8*)(ap + kn);
#pragma unroll
        for (int g = 0; g < 4; g++) {
            bf16x8 bb = *(const bf16x8*)(bp + (size_t)g * 16 * N_ + kn);
            acc[g] = __builtin_amdgcn_mfma_f32_16x16x32_bf16(a, bb, acc[g], 0, 0, 0);
        }
        if (p) accs = __builtin_amdgcn_mfma_f32_16x16x32_bf16(a, ones, accs, 0, 0, 0);
    }
    float* outp = P + (size_t)kc * PSTRIDE + (p ? POFF_G : 0) + b * (HID * HID);
#pragma unroll
    for (int g = 0; g < 4; g++)
#pragma unroll
        for (int r = 0; r < 4; r++) {
            int row = 16 * w + q * 4 + r, col = 16 * g + lr;
            outp[row * HID + col] = acc[g][r];
        }
    if (p && lr == 0) {
#pragma unroll
        for (int r = 0; r < 4; r++)
            P[(size_t)kc * PSTRIDE + POFF_S + b * HID + 16 * w + q * 4 + r] = accs[r];
    }
}

// K2b: sum the 16 k-chunk partials into contiguous M|G|S (66048 floats).
__global__ __launch_bounds__(256) void reduceMGS(
    const float* __restrict__ P, float* __restrict__ out)
{
    int idx = blockIdx.x * 256 + threadIdx.x;   // 0..66047
    if (idx >= 66048) return;
    float s = 0.f;
#pragma unroll
    for (int kc = 0; kc < NKC; kc++) s += P[(size_t)kc * PSTRIDE + idx];
    out[idx] = s;
}

// K3: fused wmk + statsk. One block per channel c; 8 waves = 8 batches in
// parallel; G-row loads vectorized f32x4.
__global__ __launch_bounds__(512) void wmstat(
    const float* __restrict__ ww, const float* __restrict__ Mm,
    const float* __restrict__ S, const float* __restrict__ G,
    const float* __restrict__ wb, const float* __restrict__ gamma,
    const float* __restrict__ beta, unsigned short* __restrict__ wmbf,
    float* __restrict__ scale, float* __restrict__ shift2)
{
    const int c = blockIdx.x;
    const int t = threadIdx.x;
    const int b = t >> 6, lane = t & 63;
    const float wbc = wb[c];
    const float* wr = ww + (size_t)c * HID;

    const float* mr = Mm + ((size_t)b * HID + lane) * HID;
    float acc = 0.f;
#pragma unroll
    for (int d = 0; d < HID; d += 4) {
        float4 m4 = *(const float4*)(mr + d);
        acc += wr[d] * m4.x + wr[d + 1] * m4.y + wr[d + 2] * m4.z + wr[d + 3] * m4.w;
    }
    unsigned short us = f2bf(acc * (1.0f / N_));
    wmbf[((size_t)b * C_ + c) * HID + lane] = us;
    float v = bf2f(us);
    float sv = S[b * HID + lane];
    float t1 = v * sv;
    for (int off = 32; off; off >>= 1) t1 += __shfl_down(t1, off);
    t1 = __shfl(t1, 0);

    const f32x4* Gb4 = (const f32x4*)(G + (size_t)b * HID * HID + (size_t)lane * HID);
    float inner = 0.f;
#pragma unroll
    for (int fo = 0; fo < 16; fo++) {
        f32x4 g4 = Gb4[fo];
        inner = fmaf(g4[0], __shfl(v, 4 * fo + 0), inner);
        inner = fmaf(g4[1], __shfl(v, 4 * fo + 1), inner);
        inner = fmaf(g4[2], __shfl(v, 4 * fo + 2), inner);
        inner = fmaf(g4[3], __shfl(v, 4 * fo + 3), inner);
    }
    float qq = v * inner;
    for (int off = 32; off; off >>= 1) qq += __shfl_down(qq, off);
    qq = __shfl(qq, 0);

    __shared__ float red[16];
    if (lane == 0) {
        red[b] = t1;
        red[8 + b] = qq + 2.f * wbc * t1;
    }
    __syncthreads();
    if (t == 0) {
        float asum = 0.f, asq = 0.f;
#pragma unroll
        for (int i = 0; i < 8; i++) { asum += red[i]; asq += red[8 + i]; }
        const float cnt = (float)B_ * (float)N_;
        const float inv = 1.0f / cnt;
        float mean = (asum + cnt * wbc) * inv;
        float e2   = (asq + cnt * wbc * wbc) * inv;
        float var  = e2 - mean * mean;
        float sc   = gamma[c] * rsqrtf(var + 1e-5f);
        scale[c]  = sc;
        shift2[c] = beta[c] - mean * sc + sc * wbc;
    }
}

// K4: out = sc[c]*(Wm[b][c][:]·theta[:,n]) + sh[c] + x  (float4 stores along n)
__global__ __launch_bounds__(256) void finalk_mfma(
    const unsigned short* __restrict__ wmbf, const unsigned short* __restrict__ thT,
    const float* __restrict__ x, const float* __restrict__ scale,
    const float* __restrict__ shift2, float* __restrict__ out)
{
    const int b = blockIdx.z, c0 = blockIdx.y * 64, n0 = blockIdx.x * 64;
    const int t = threadIdx.x, w = t >> 6, L = t & 63;
    const int lr = L & 15, q = L >> 4;

    const unsigned short* ap = thT + ((size_t)b * N_ + n0 + 16 * w + lr) * HID + q * 8;
    const unsigned short* bp = wmbf + ((size_t)b * C_ + c0 + lr) * HID + q * 8;

    float4 xv[4];
    size_t xoff[4];
#pragma unroll
    for (int g = 0; g < 4; g++) {
        xoff[g] = ((size_t)b * C_ + c0 + 16 * g + lr) * N_ + n0 + 16 * w + q * 4;
        xv[g] = *(const float4*)(x + xoff[g]);
    }

    bf16x8 A0 = *(const bf16x8*)(ap);
    bf16x8 A1 = *(const bf16x8*)(ap + 32);
    f32x4 acc[4] = {};
#pragma unroll
    for (int g = 0; g < 4; g++) {
        bf16x8 Bg0 = *(const bf16x8*)(bp + (size_t)g * 16 * HID);
        bf16x8 Bg1 = *(const bf16x8*)(bp + (size_t)g * 16 * HID + 32);
        acc[g] = __builtin_amdgcn_mfma_f32_16x16x32_bf16(A0, Bg0, acc[g], 0, 0, 0);
        acc[g] = __builtin_amdgcn_mfma_f32_16x16x32_bf16(A1, Bg1, acc[g], 0, 0, 0);
    }
#pragma unroll
    for (int g = 0; g < 4; g++) {
        int c = c0 + 16 * g + lr;
        float sc = scale[c], sh = shift2[c];
        float4 o;
        o.x = fmaf(sc, acc[g][0], sh) + xv[g].x;
        o.y = fmaf(sc, acc[g][1], sh) + xv[g].y;
        o.z = fmaf(sc, acc[g][2], sh) + xv[g].z;
        o.w = fmaf(sc, acc[g][3], sh) + xv[g].w;
        *(float4*)(out + xoff[g]) = o;
    }
}

extern "C" void kernel_launch(void* const* d_in, const int* in_sizes, int n_in,
                              void* d_out, int out_size, void* d_ws, size_t ws_size,
                              hipStream_t stream)
{
    const float* x  = (const float*)d_in[0];
    const float* tw = (const float*)d_in[1];
    const float* tb = (const float*)d_in[2];
    const float* pw = (const float*)d_in[3];
    const float* pb = (const float*)d_in[4];
    const float* gw = (const float*)d_in[5];
    const float* gb = (const float*)d_in[6];
    const float* ww = (const float*)d_in[7];
    const float* wb = (const float*)d_in[8];
    const float* gamma = (const float*)d_in[9];
    const float* beta  = (const float*)d_in[10];
    float* out = (float*)d_out;

    char* ws = (char*)d_ws;
    unsigned short* wbf   = (unsigned short*)(ws + WSB_WBF);
    unsigned short* tpgbf = (unsigned short*)(ws + WSB_TPG);
    unsigned short* thT   = (unsigned short*)(ws + WSB_THT);
    float* Mm   = (float*)(ws + WSB_M);
    float* Gg   = (float*)(ws + WSB_G);
    float* S    = (float*)(ws + WSB_S);
    unsigned short* wmbf = (unsigned short*)(ws + WSB_WMBF);
    float* scl  = (float*)(ws + WSB_SC);
    float* shf  = (float*)(ws + WSB_SH);
    unsigned short* xT = (unsigned short*)(ws + WSB_XT);
    float* P    = (float*)(ws + WSB_P);

    prep<<<dim3(32, 16, 9), 256, 0, stream>>>(x, xT, tw, pw, gw, wbf);
    proj_mfma<<<dim3(32, 2, B_), 256, 0, stream>>>(xT, wbf, tb, pb, gb, tpgbf, thT);
    gram_mfma<<<dim3(NKC, 2, B_), 256, 0, stream>>>(tpgbf, P);
    reduceMGS<<<dim3(259), 256, 0, stream>>>(P, Mm);
    wmstat<<<C_, 512, 0, stream>>>(ww, Mm, S, Gg, wb, gamma, beta, wmbf, scl, shf);
    finalk_mfma<<<dim3(32, 16, B_), 256, 0, stream>>>(wmbf, thT, x, scl, shf, out);
}